// Round 1
// baseline (1231.349 us; speedup 1.0000x reference)
//
#include <hip/hip_runtime.h>

// 2-layer stacked LSTM: B=256, T=2048, H=64, layer2 hidden=1.
// One block per batch element (256 blocks = 256 CUs), 320 threads (5 waves):
//   waves 0-3 : 256 gate columns of layer 1 (W1 column register-resident)
//   wave 2    : also does the c1/h1 update in phase 2
//   wave 4    : layer 2 for step t-1, overlapped with layer-1 phase 1 of step t
constexpr int kT = 2048;
constexpr int kB = 256;
constexpr int kH = 64;

__device__ __forceinline__ float fast_sig(float x) {
    // 1 / (1 + e^-x); rcp(inf)=0 handles saturation correctly
    return __builtin_amdgcn_rcpf(1.0f + __expf(-x));
}
__device__ __forceinline__ float fast_tanh(float x) {
    // 1 - 2/(e^{2x}+1); exp->inf => 1, exp->0 => -1
    float t = __expf(2.0f * x);
    return 1.0f - 2.0f * __builtin_amdgcn_rcpf(t + 1.0f);
}

__global__ __launch_bounds__(320) void lstm2_kernel(
    const float* __restrict__ x, const float* __restrict__ W1,
    const float* __restrict__ b1, const float* __restrict__ W2,
    const float* __restrict__ b2, float* __restrict__ out)
{
    __shared__ float x_lds[kT];          // whole input row for this batch elem
    __shared__ float h1_lds[2][kH];      // double-buffered h1
    __shared__ float a_lds[4 * kH];      // activated gate values i,j,f,o

    const int tid = threadIdx.x;
    const int b = blockIdx.x;
    const float* xg = x + (size_t)b * kT;
    float* outg = out + (size_t)b * kT;

    // --- preload x row, zero-init h1 buffers ---
    for (int i = tid; i < kT; i += 320) x_lds[i] = xg[i];
    if (tid < kH) { h1_lds[0][tid] = 0.0f; h1_lds[1][tid] = 0.0f; }

    // --- per-role register state ---
    float w0 = 0.0f, b1g = 0.0f;   // layer-1 column weights (waves 0-3)
    float wh[kH];
    float c1 = 0.0f;               // layer-1 cell state (wave 2, u = tid&63)
    float4 w2u = {0, 0, 0, 0}, w2t = {0, 0, 0, 0}, b2v = {0, 0, 0, 0};
    float c2 = 0.0f, h2 = 0.0f;    // layer-2 state (wave 4, uniform)

    if (tid < 256) {
        w0  = W1[tid];             // row 0: x weight
        b1g = b1[tid];
        #pragma unroll
        for (int k = 0; k < kH; ++k) wh[k] = W1[(k + 1) * 256 + tid];
    } else {
        const int u = tid - 256;
        w2u = ((const float4*)W2)[u];    // W2[u][0..3]
        w2t = ((const float4*)W2)[kH];   // W2[64][0..3] (h2 recurrent weight)
        b2v = ((const float4*)b2)[0];
    }
    __syncthreads();

    int cur = 0;
    for (int t = 0; t < kT; ++t) {
        const int nxt = cur ^ 1;
        if (tid < 256) {
            // ---- layer-1 gate pre-activation for step t ----
            float z = fmaf(x_lds[t], w0, b1g);
            const float4* h4 = (const float4*)h1_lds[cur];
            #pragma unroll
            for (int k = 0; k < kH / 4; ++k) {
                float4 h = h4[k];  // wave-uniform broadcast read
                z = fmaf(h.x, wh[4 * k + 0], z);
                z = fmaf(h.y, wh[4 * k + 1], z);
                z = fmaf(h.z, wh[4 * k + 2], z);
                z = fmaf(h.w, wh[4 * k + 3], z);
            }
            const int gate = tid >> 6;   // 0:i 1:j 2:f 3:o (wave-uniform)
            float a;
            if (gate == 1)      a = fast_tanh(z);
            else if (gate == 2) a = fast_sig(z + 1.0f);  // forget bias
            else                a = fast_sig(z);
            a_lds[tid] = a;
        } else if (t > 0) {
            // ---- layer 2 for step t-1 (pipelined; reads h1(t-1)=h1_lds[cur]) ----
            const int u = tid - 256;
            const float hv = h1_lds[cur][u];
            float p0 = hv * w2u.x, p1 = hv * w2u.y, p2 = hv * w2u.z, p3 = hv * w2u.w;
            #pragma unroll
            for (int m = 1; m < 64; m <<= 1) {
                p0 += __shfl_xor(p0, m);
                p1 += __shfl_xor(p1, m);
                p2 += __shfl_xor(p2, m);
                p3 += __shfl_xor(p3, m);
            }
            const float zi = p0 + h2 * w2t.x + b2v.x;
            const float zj = p1 + h2 * w2t.y + b2v.y;
            const float zf = p2 + h2 * w2t.z + b2v.z;
            const float zo = p3 + h2 * w2t.w + b2v.w;
            c2 = fast_sig(zf + 1.0f) * c2 + fast_sig(zi) * fast_tanh(zj);
            h2 = fast_sig(zo) * fast_tanh(c2);
            if (u == 0) outg[t - 1] = h2;
        }
        __syncthreads();
        if ((tid >> 6) == 2) {
            // ---- c1/h1 update on wave 2 (SIMD2; wave4/layer2 sits on SIMD0) ----
            const int u = tid & 63;
            const float ai = a_lds[u];
            const float aj = a_lds[64 + u];
            const float af = a_lds[128 + u];
            const float ao = a_lds[192 + u];
            c1 = fmaf(af, c1, ai * aj);
            h1_lds[nxt][u] = ao * fast_tanh(c1);
        }
        __syncthreads();
        cur = nxt;
    }

    // ---- epilogue: layer 2 for final step T-1 ----
    if (tid >= 256) {
        const int u = tid - 256;
        const float hv = h1_lds[cur][u];
        float p0 = hv * w2u.x, p1 = hv * w2u.y, p2 = hv * w2u.z, p3 = hv * w2u.w;
        #pragma unroll
        for (int m = 1; m < 64; m <<= 1) {
            p0 += __shfl_xor(p0, m);
            p1 += __shfl_xor(p1, m);
            p2 += __shfl_xor(p2, m);
            p3 += __shfl_xor(p3, m);
        }
        const float zi = p0 + h2 * w2t.x + b2v.x;
        const float zj = p1 + h2 * w2t.y + b2v.y;
        const float zf = p2 + h2 * w2t.z + b2v.z;
        const float zo = p3 + h2 * w2t.w + b2v.w;
        c2 = fast_sig(zf + 1.0f) * c2 + fast_sig(zi) * fast_tanh(zj);
        h2 = fast_sig(zo) * fast_tanh(c2);
        if (u == 0) outg[kT - 1] = h2;
    }
}

extern "C" void kernel_launch(void* const* d_in, const int* in_sizes, int n_in,
                              void* d_out, int out_size, void* d_ws, size_t ws_size,
                              hipStream_t stream) {
    const float* x  = (const float*)d_in[0];
    const float* W1 = (const float*)d_in[1];
    const float* b1 = (const float*)d_in[2];
    const float* W2 = (const float*)d_in[3];
    const float* b2 = (const float*)d_in[4];
    float* out = (float*)d_out;
    lstm2_kernel<<<kB, 320, 0, stream>>>(x, W1, b1, W2, b2, out);
}

// Round 2
// 1133.770 us; speedup vs baseline: 1.0861x; 1.0861x over previous
//
#include <hip/hip_runtime.h>

// 2-layer stacked LSTM: B=256, T=2048, H=64, layer2 hidden=1.
// One block per batch element (256 blocks = 256 CUs), 320 threads (5 waves).
// Waves 0-3: layer 1. Wave w, lane l owns unit u = 16w + (l&15), gate g = l>>4
//   (so all 4 gates of a unit live in ONE wave -> gate gather via __shfl,
//   no barrier between gate compute and the c1/h1 update).
// Wave 4: layer 2, 2-stage software pipeline (stage A: butterfly dot for
//   step t-1; stage B: recurrent c2/h2 update for step t-2).
// ONE __syncthreads per step (publishes h1 for the next step).
constexpr int kT = 2048;
constexpr int kB = 256;
constexpr int kH = 64;

__device__ __forceinline__ float fast_sig(float x) {
    // 1 / (1 + e^-x); rcp(inf)=0 handles saturation correctly
    return __builtin_amdgcn_rcpf(1.0f + __expf(-x));
}
__device__ __forceinline__ float fast_tanh(float x) {
    // 1 - 2/(e^{2x}+1)
    float t = __expf(2.0f * x);
    return 1.0f - 2.0f * __builtin_amdgcn_rcpf(t + 1.0f);
}

__global__ __launch_bounds__(320) void lstm2_kernel(
    const float* __restrict__ x, const float* __restrict__ W1,
    const float* __restrict__ b1, const float* __restrict__ W2,
    const float* __restrict__ b2, float* __restrict__ out)
{
    __shared__ float x_lds[kT];       // whole input row for this batch elem
    __shared__ float h1_lds[2][kH];   // double-buffered h1

    const int tid = threadIdx.x;
    const int b = blockIdx.x;
    const float* xg = x + (size_t)b * kT;
    float* outg = out + (size_t)b * kT;

    for (int i = tid; i < kT; i += 320) x_lds[i] = xg[i];
    if (tid < kH) { h1_lds[0][tid] = 0.0f; h1_lds[1][tid] = 0.0f; }

    const int w = tid >> 6;   // wave id 0..4
    const int l = tid & 63;   // lane

    // ---- layer-1 per-lane state (waves 0-3) ----
    float w0 = 0.0f, b1g = 0.0f;
    float wh[kH];
    float c1 = 0.0f;
    int u = 0, g = 0;

    // ---- layer-2 per-lane state (wave 4) ----
    float w2p0 = 0, w2p1 = 0, w2p2 = 0, w2p3 = 0;
    float4 w2t = {0, 0, 0, 0}, b2v = {0, 0, 0, 0};
    float c2 = 0.0f, h2 = 0.0f;
    float zi_s = 0, zj_s = 0, zf_s = 0, zo_s = 0;   // staged pre-activations

    if (w < 4) {
        g = l >> 4;
        u = 16 * w + (l & 15);
        const int col = g * 64 + u;      // gate-major columns: i,j,f,o blocks
        w0 = W1[col];
        b1g = b1[col];
        #pragma unroll
        for (int k = 0; k < kH; ++k) wh[k] = W1[(k + 1) * 256 + col];
    } else {
        const int s = l & 15, gg = l >> 4;       // slice, gate
        w2p0 = W2[(s +  0) * 4 + gg];
        w2p1 = W2[(s + 16) * 4 + gg];
        w2p2 = W2[(s + 32) * 4 + gg];
        w2p3 = W2[(s + 48) * 4 + gg];
        w2t = ((const float4*)W2)[kH];   // W2[64][0..3] (h2 recurrent row)
        b2v = ((const float4*)b2)[0];
    }
    __syncthreads();

    int cur = 0;
    for (int t = 0; t < kT; ++t) {
        const int nxt = cur ^ 1;
        if (w < 4) {
            // ---- layer-1 step t: z = [x_t, h1(t-1)] . W1col + b ----
            const float xt = x_lds[t];
            float z0 = fmaf(xt, w0, b1g), z1 = 0.0f, z2 = 0.0f, z3 = 0.0f;
            const float4* h4 = (const float4*)h1_lds[cur];
            #pragma unroll
            for (int k = 0; k < 16; ++k) {
                float4 h = h4[k];   // identical address across wave: broadcast
                z0 = fmaf(h.x, wh[4 * k + 0], z0);
                z1 = fmaf(h.y, wh[4 * k + 1], z1);
                z2 = fmaf(h.z, wh[4 * k + 2], z2);
                z3 = fmaf(h.w, wh[4 * k + 3], z3);
            }
            float z = (z0 + z1) + (z2 + z3);
            // activation (predicated, no branch): g==1 -> tanh=2*sig(2z)-1,
            // g==2 -> sigmoid(z + forget_bias), else sigmoid(z)
            float zz = (g == 1) ? 2.0f * z : ((g == 2) ? z + 1.0f : z);
            float sg = fast_sig(zz);
            float a = (g == 1) ? fmaf(2.0f, sg, -1.0f) : sg;
            // gather the 4 gates of unit u (all in this wave)
            const int base = l & 15;
            const float ai = __shfl(a, base);
            const float aj = __shfl(a, base + 16);
            const float af = __shfl(a, base + 32);
            const float ao = __shfl(a, base + 48);
            c1 = fmaf(af, c1, ai * aj);               // redundant in 4 lanes
            const float h1n = ao * fast_tanh(c1);
            if (g == 0) h1_lds[nxt][u] = h1n;
        } else {
            // ---- stage B: recurrent update for step t-2 (uses staged z) ----
            if (t >= 2) {
                const float zi = zi_s + h2 * w2t.x;
                const float zj = zj_s + h2 * w2t.y;
                const float zf = zf_s + h2 * w2t.z;
                const float zo = zo_s + h2 * w2t.w;
                c2 = fast_sig(zf + 1.0f) * c2 + fast_sig(zi) * fast_tanh(zj);
                h2 = fast_sig(zo) * fast_tanh(c2);
                if (l == 0) outg[t - 2] = h2;
            }
            // ---- stage A: dot products for step t-1 (h1(t-1)=h1_lds[cur]) --
            if (t >= 1) {
                const int s = l & 15;
                const float* hb = h1_lds[cur];
                float p = hb[s] * w2p0;
                p = fmaf(hb[s + 16], w2p1, p);
                p = fmaf(hb[s + 32], w2p2, p);
                p = fmaf(hb[s + 48], w2p3, p);
                p += __shfl_xor(p, 1);
                p += __shfl_xor(p, 2);
                p += __shfl_xor(p, 4);
                p += __shfl_xor(p, 8);
                zi_s = __shfl(p, s)      + b2v.x;
                zj_s = __shfl(p, s + 16) + b2v.y;
                zf_s = __shfl(p, s + 32) + b2v.z;
                zo_s = __shfl(p, s + 48) + b2v.w;
            }
        }
        __syncthreads();
        cur = nxt;
    }

    // ---- epilogue (wave 4): finish steps T-2 and T-1 ----
    if (w == 4) {
        // stage B for T-2 (staged in last loop iteration)
        {
            const float zi = zi_s + h2 * w2t.x;
            const float zj = zj_s + h2 * w2t.y;
            const float zf = zf_s + h2 * w2t.z;
            const float zo = zo_s + h2 * w2t.w;
            c2 = fast_sig(zf + 1.0f) * c2 + fast_sig(zi) * fast_tanh(zj);
            h2 = fast_sig(zo) * fast_tanh(c2);
            if (l == 0) outg[kT - 2] = h2;
        }
        // stage A + B for T-1 (h1(T-1) is in h1_lds[cur] after the loop)
        {
            const int s = l & 15;
            const float* hb = h1_lds[cur];
            float p = hb[s] * w2p0;
            p = fmaf(hb[s + 16], w2p1, p);
            p = fmaf(hb[s + 32], w2p2, p);
            p = fmaf(hb[s + 48], w2p3, p);
            p += __shfl_xor(p, 1);
            p += __shfl_xor(p, 2);
            p += __shfl_xor(p, 4);
            p += __shfl_xor(p, 8);
            const float zi = __shfl(p, s)      + b2v.x + h2 * w2t.x;
            const float zj = __shfl(p, s + 16) + b2v.y + h2 * w2t.y;
            const float zf = __shfl(p, s + 32) + b2v.z + h2 * w2t.z;
            const float zo = __shfl(p, s + 48) + b2v.w + h2 * w2t.w;
            c2 = fast_sig(zf + 1.0f) * c2 + fast_sig(zi) * fast_tanh(zj);
            h2 = fast_sig(zo) * fast_tanh(c2);
            if (l == 0) outg[kT - 1] = h2;
        }
    }
}

extern "C" void kernel_launch(void* const* d_in, const int* in_sizes, int n_in,
                              void* d_out, int out_size, void* d_ws, size_t ws_size,
                              hipStream_t stream) {
    const float* x  = (const float*)d_in[0];
    const float* W1 = (const float*)d_in[1];
    const float* b1 = (const float*)d_in[2];
    const float* W2 = (const float*)d_in[3];
    const float* b2 = (const float*)d_in[4];
    float* out = (float*)d_out;
    lstm2_kernel<<<kB, 320, 0, stream>>>(x, W1, b1, W2, b2, out);
}

// Round 3
// 1125.307 us; speedup vs baseline: 1.0942x; 1.0075x over previous
//
#include <hip/hip_runtime.h>

// 2-layer stacked LSTM: B=256, T=2048, H=64, layer2 hidden=1.
// One block per batch element (256 blocks = 256 CUs), 320 threads (5 waves).
// Waves 0-3: layer 1. Wave w, lane l owns unit u = 16w + (l&15), gate g = l>>4
//   (all 4 gates of a unit in ONE wave -> gate gather via __shfl, no barrier
//   between gate compute and the c1/h1 update).
// Wave 4: layer 2, 2-stage software pipeline (stage A: butterfly dot for
//   step t-1; stage B: recurrent c2/h2 update for step t-2).
// ONE __syncthreads per step (publishes h1 for the next step).
//
// __launch_bounds__(320, 2): min 2 waves/EU -> 256-VGPR budget. Without this
// the backend targets 8 waves/EU (64 VGPRs) and REMATERIALIZES the 64 W1
// weights from global memory every timestep (round-1/2 defect: VGPR_Count=64,
// ~1330 cyc/step). 2 waves/EU also guarantees SIMD0 can host wave0+wave4.
constexpr int kT = 2048;
constexpr int kB = 256;
constexpr int kH = 64;

__device__ __forceinline__ float fast_sig(float x) {
    return __builtin_amdgcn_rcpf(1.0f + __expf(-x));
}
__device__ __forceinline__ float fast_tanh(float x) {
    float t = __expf(2.0f * x);
    return 1.0f - 2.0f * __builtin_amdgcn_rcpf(t + 1.0f);
}

__global__ __launch_bounds__(320, 2) void lstm2_kernel(
    const float* __restrict__ x, const float* __restrict__ W1,
    const float* __restrict__ b1, const float* __restrict__ W2,
    const float* __restrict__ b2, float* __restrict__ out)
{
    __shared__ float x_lds[kT];       // whole input row for this batch elem
    __shared__ float h1_lds[2][kH];   // double-buffered h1

    const int tid = threadIdx.x;
    const int b = blockIdx.x;
    const float* xg = x + (size_t)b * kT;
    float* outg = out + (size_t)b * kT;

    for (int i = tid; i < kT; i += 320) x_lds[i] = xg[i];
    if (tid < kH) { h1_lds[0][tid] = 0.0f; h1_lds[1][tid] = 0.0f; }

    const int w = tid >> 6;   // wave id 0..4
    const int l = tid & 63;   // lane

    // ---- layer-1 per-lane state (waves 0-3): column weights in registers ----
    float w0 = 0.0f, b1g = 0.0f;
    float4 wh4[16];           // 64 weights -> 64 VGPRs (SROA, constant indices)
    #pragma unroll
    for (int k = 0; k < 16; ++k) wh4[k] = make_float4(0.f, 0.f, 0.f, 0.f);
    float c1 = 0.0f;
    int u = 0, g = 0;

    // ---- layer-2 per-lane state (wave 4) ----
    float w2p0 = 0, w2p1 = 0, w2p2 = 0, w2p3 = 0;
    float4 w2t = {0, 0, 0, 0}, b2v = {0, 0, 0, 0};
    float c2 = 0.0f, h2 = 0.0f;
    float zi_s = 0, zj_s = 0, zf_s = 0, zo_s = 0;   // staged pre-activations

    if (w < 4) {
        g = l >> 4;
        u = 16 * w + (l & 15);
        const int col = g * 64 + u;      // gate-major columns: i,j,f,o blocks
        w0 = W1[col];
        b1g = b1[col];
        #pragma unroll
        for (int k = 0; k < 16; ++k) {
            wh4[k].x = W1[(4 * k + 1) * 256 + col];
            wh4[k].y = W1[(4 * k + 2) * 256 + col];
            wh4[k].z = W1[(4 * k + 3) * 256 + col];
            wh4[k].w = W1[(4 * k + 4) * 256 + col];
        }
    } else {
        const int s = l & 15, gg = l >> 4;       // slice, gate
        w2p0 = W2[(s +  0) * 4 + gg];
        w2p1 = W2[(s + 16) * 4 + gg];
        w2p2 = W2[(s + 32) * 4 + gg];
        w2p3 = W2[(s + 48) * 4 + gg];
        w2t = ((const float4*)W2)[kH];   // W2[64][0..3] (h2 recurrent row)
        b2v = ((const float4*)b2)[0];
    }
    __syncthreads();

    int cur = 0;
    for (int t = 0; t < kT; ++t) {
        const int nxt = cur ^ 1;
        if (w < 4) {
            // ---- layer-1 step t: z = [x_t, h1(t-1)] . W1col + b ----
            const float xt = x_lds[t];
            float z0 = fmaf(xt, w0, b1g), z1 = 0.0f, z2 = 0.0f, z3 = 0.0f;
            const float4* h4 = (const float4*)h1_lds[cur];
            #pragma unroll
            for (int k = 0; k < 16; ++k) {
                float4 h = h4[k];   // identical address across wave: broadcast
                z0 = fmaf(h.x, wh4[k].x, z0);
                z1 = fmaf(h.y, wh4[k].y, z1);
                z2 = fmaf(h.z, wh4[k].z, z2);
                z3 = fmaf(h.w, wh4[k].w, z3);
            }
            float z = (z0 + z1) + (z2 + z3);
            // g==1 -> tanh(z) = 2*sig(2z)-1; g==2 -> sig(z+1); else sig(z)
            float zz = (g == 1) ? 2.0f * z : ((g == 2) ? z + 1.0f : z);
            float sg = fast_sig(zz);
            float a = (g == 1) ? fmaf(2.0f, sg, -1.0f) : sg;
            // gather the 4 gates of unit u (all in this wave)
            const int base = l & 15;
            const float ai = __shfl(a, base);
            const float aj = __shfl(a, base + 16);
            const float af = __shfl(a, base + 32);
            const float ao = __shfl(a, base + 48);
            c1 = fmaf(af, c1, ai * aj);               // redundant in 4 lanes
            const float h1n = ao * fast_tanh(c1);
            if (g == 0) h1_lds[nxt][u] = h1n;
        } else {
            // ---- stage B: recurrent update for step t-2 (uses staged z) ----
            if (t >= 2) {
                const float zi = zi_s + h2 * w2t.x;
                const float zj = zj_s + h2 * w2t.y;
                const float zf = zf_s + h2 * w2t.z;
                const float zo = zo_s + h2 * w2t.w;
                c2 = fast_sig(zf + 1.0f) * c2 + fast_sig(zi) * fast_tanh(zj);
                h2 = fast_sig(zo) * fast_tanh(c2);
                if (l == 0) outg[t - 2] = h2;
            }
            // ---- stage A: dot products for step t-1 (h1(t-1)=h1_lds[cur]) --
            if (t >= 1) {
                const int s = l & 15;
                const float* hb = h1_lds[cur];
                float p = hb[s] * w2p0;
                p = fmaf(hb[s + 16], w2p1, p);
                p = fmaf(hb[s + 32], w2p2, p);
                p = fmaf(hb[s + 48], w2p3, p);
                p += __shfl_xor(p, 1);
                p += __shfl_xor(p, 2);
                p += __shfl_xor(p, 4);
                p += __shfl_xor(p, 8);
                zi_s = __shfl(p, s)      + b2v.x;
                zj_s = __shfl(p, s + 16) + b2v.y;
                zf_s = __shfl(p, s + 32) + b2v.z;
                zo_s = __shfl(p, s + 48) + b2v.w;
            }
        }
        __syncthreads();
        cur = nxt;
    }

    // ---- epilogue (wave 4): finish steps T-2 and T-1 ----
    if (w == 4) {
        {
            const float zi = zi_s + h2 * w2t.x;
            const float zj = zj_s + h2 * w2t.y;
            const float zf = zf_s + h2 * w2t.z;
            const float zo = zo_s + h2 * w2t.w;
            c2 = fast_sig(zf + 1.0f) * c2 + fast_sig(zi) * fast_tanh(zj);
            h2 = fast_sig(zo) * fast_tanh(c2);
            if (l == 0) outg[kT - 2] = h2;
        }
        {
            const int s = l & 15;
            const float* hb = h1_lds[cur];
            float p = hb[s] * w2p0;
            p = fmaf(hb[s + 16], w2p1, p);
            p = fmaf(hb[s + 32], w2p2, p);
            p = fmaf(hb[s + 48], w2p3, p);
            p += __shfl_xor(p, 1);
            p += __shfl_xor(p, 2);
            p += __shfl_xor(p, 4);
            p += __shfl_xor(p, 8);
            const float zi = __shfl(p, s)      + b2v.x + h2 * w2t.x;
            const float zj = __shfl(p, s + 16) + b2v.y + h2 * w2t.y;
            const float zf = __shfl(p, s + 32) + b2v.z + h2 * w2t.z;
            const float zo = __shfl(p, s + 48) + b2v.w + h2 * w2t.w;
            c2 = fast_sig(zf + 1.0f) * c2 + fast_sig(zi) * fast_tanh(zj);
            h2 = fast_sig(zo) * fast_tanh(c2);
            if (l == 0) outg[kT - 1] = h2;
        }
    }
}

extern "C" void kernel_launch(void* const* d_in, const int* in_sizes, int n_in,
                              void* d_out, int out_size, void* d_ws, size_t ws_size,
                              hipStream_t stream) {
    const float* x  = (const float*)d_in[0];
    const float* W1 = (const float*)d_in[1];
    const float* b1 = (const float*)d_in[2];
    const float* W2 = (const float*)d_in[3];
    const float* b2 = (const float*)d_in[4];
    float* out = (float*)d_out;
    lstm2_kernel<<<kB, 320, 0, stream>>>(x, W1, b1, W2, b2, out);
}

// Round 4
// 1097.766 us; speedup vs baseline: 1.1217x; 1.0251x over previous
//
#include <hip/hip_runtime.h>

// 2-layer stacked LSTM: B=256, T=2048, H=64, layer2 hidden=1.
// One block per batch element (256 blocks = 256 CUs), 320 threads (5 waves).
// Waves 0-3: layer 1. Wave w, lane l owns unit u = 16w + (l&15), gate g = l>>4
//   (all 4 gates of a unit in ONE wave -> gate gather via __shfl, no barrier
//   between gate compute and the c1/h1 update).
// Wave 4: layer 2, 2-stage software pipeline (stage A: butterfly dot for
//   step t-1; stage B: recurrent c2/h2 update for step t-2).
// ONE __syncthreads per step (publishes h1 for the next step).
//
// Round-3 post-mortem: VGPR_Count stayed 64 => the 64 W1 column weights were
// NOT register-resident; the backend re-fetched them every timestep chasing
// 8-waves/EU occupancy. Fix: amdgpu_waves_per_eu(1) (512-VGPR budget) plus an
// opaque asm pin that makes rematerialization of the weight loads illegal.
constexpr int kT = 2048;
constexpr int kB = 256;
constexpr int kH = 64;

__device__ __forceinline__ float fast_sig(float x) {
    return __builtin_amdgcn_rcpf(1.0f + __expf(-x));
}
__device__ __forceinline__ float fast_tanh(float x) {
    float t = __expf(2.0f * x);
    return 1.0f - 2.0f * __builtin_amdgcn_rcpf(t + 1.0f);
}

__global__ __launch_bounds__(320)
__attribute__((amdgpu_waves_per_eu(1)))
void lstm2_kernel(
    const float* __restrict__ x, const float* __restrict__ W1,
    const float* __restrict__ b1, const float* __restrict__ W2,
    const float* __restrict__ b2, float* __restrict__ out)
{
    __shared__ float x_lds[kT];       // whole input row for this batch elem
    __shared__ float h1_lds[2][kH];   // double-buffered h1

    const int tid = threadIdx.x;
    const int b = blockIdx.x;
    const float* xg = x + (size_t)b * kT;
    float* outg = out + (size_t)b * kT;

    for (int i = tid; i < kT; i += 320) x_lds[i] = xg[i];
    if (tid < kH) { h1_lds[0][tid] = 0.0f; h1_lds[1][tid] = 0.0f; }

    const int w = tid >> 6;   // wave id 0..4
    const int l = tid & 63;   // lane

    // ---- layer-1 per-lane state (waves 0-3): column weights in registers ----
    float w0 = 0.0f, b1g = 0.0f;
    float4 wh4[16];           // 64 weights -> 64 VGPRs, pinned below
    #pragma unroll
    for (int k = 0; k < 16; ++k) wh4[k] = make_float4(0.f, 0.f, 0.f, 0.f);
    float c1 = 0.0f;
    int u = 0, g = 0;

    // ---- layer-2 per-lane state (wave 4) ----
    float w2p0 = 0, w2p1 = 0, w2p2 = 0, w2p3 = 0;
    float4 w2t = {0, 0, 0, 0}, b2v = {0, 0, 0, 0};
    float c2 = 0.0f, h2 = 0.0f;
    float zi_s = 0, zj_s = 0, zf_s = 0, zo_s = 0;   // staged pre-activations

    if (w < 4) {
        g = l >> 4;
        u = 16 * w + (l & 15);
        const int col = g * 64 + u;      // gate-major columns: i,j,f,o blocks
        w0 = W1[col];
        b1g = b1[col];
        #pragma unroll
        for (int k = 0; k < 16; ++k) {
            wh4[k].x = W1[(4 * k + 1) * 256 + col];
            wh4[k].y = W1[(4 * k + 2) * 256 + col];
            wh4[k].z = W1[(4 * k + 3) * 256 + col];
            wh4[k].w = W1[(4 * k + 4) * 256 + col];
        }
    } else {
        const int s = l & 15, gg = l >> 4;       // slice, gate
        w2p0 = W2[(s +  0) * 4 + gg];
        w2p1 = W2[(s + 16) * 4 + gg];
        w2p2 = W2[(s + 32) * 4 + gg];
        w2p3 = W2[(s + 48) * 4 + gg];
        w2t = ((const float4*)W2)[kH];   // W2[64][0..3] (h2 recurrent row)
        b2v = ((const float4*)b2)[0];
    }

    // ---- PIN all loop-invariant weights into VGPRs. The empty asm is an
    // opaque read-modify-write: the compiler cannot rematerialize the global
    // loads past it, so these 78 values must stay live across the t-loop. ----
    #pragma unroll
    for (int k = 0; k < 16; ++k)
        asm volatile("" : "+v"(wh4[k].x), "+v"(wh4[k].y),
                          "+v"(wh4[k].z), "+v"(wh4[k].w));
    asm volatile("" : "+v"(w0), "+v"(b1g));
    asm volatile("" : "+v"(w2p0), "+v"(w2p1), "+v"(w2p2), "+v"(w2p3));
    asm volatile("" : "+v"(w2t.x), "+v"(w2t.y), "+v"(w2t.z), "+v"(w2t.w));
    asm volatile("" : "+v"(b2v.x), "+v"(b2v.y), "+v"(b2v.z), "+v"(b2v.w));

    __syncthreads();

    int cur = 0;
    for (int t = 0; t < kT; ++t) {
        const int nxt = cur ^ 1;
        if (w < 4) {
            // ---- layer-1 step t: z = [x_t, h1(t-1)] . W1col + b ----
            const float xt = x_lds[t];
            float z0 = fmaf(xt, w0, b1g), z1 = 0.0f, z2 = 0.0f, z3 = 0.0f;
            const float4* h4 = (const float4*)h1_lds[cur];
            #pragma unroll
            for (int k = 0; k < 16; ++k) {
                float4 h = h4[k];   // identical address across wave: broadcast
                z0 = fmaf(h.x, wh4[k].x, z0);
                z1 = fmaf(h.y, wh4[k].y, z1);
                z2 = fmaf(h.z, wh4[k].z, z2);
                z3 = fmaf(h.w, wh4[k].w, z3);
            }
            float z = (z0 + z1) + (z2 + z3);
            // g==1 -> tanh(z) = 2*sig(2z)-1; g==2 -> sig(z+1); else sig(z)
            float zz = (g == 1) ? 2.0f * z : ((g == 2) ? z + 1.0f : z);
            float sg = fast_sig(zz);
            float a = (g == 1) ? fmaf(2.0f, sg, -1.0f) : sg;
            // gather the 4 gates of unit u (all in this wave)
            const int base = l & 15;
            const float ai = __shfl(a, base);
            const float aj = __shfl(a, base + 16);
            const float af = __shfl(a, base + 32);
            const float ao = __shfl(a, base + 48);
            c1 = fmaf(af, c1, ai * aj);               // redundant in 4 lanes
            const float h1n = ao * fast_tanh(c1);
            if (g == 0) h1_lds[nxt][u] = h1n;
        } else {
            // ---- stage B: recurrent update for step t-2 (uses staged z) ----
            if (t >= 2) {
                const float zi = zi_s + h2 * w2t.x;
                const float zj = zj_s + h2 * w2t.y;
                const float zf = zf_s + h2 * w2t.z;
                const float zo = zo_s + h2 * w2t.w;
                c2 = fast_sig(zf + 1.0f) * c2 + fast_sig(zi) * fast_tanh(zj);
                h2 = fast_sig(zo) * fast_tanh(c2);
                if (l == 0) outg[t - 2] = h2;
            }
            // ---- stage A: dot products for step t-1 (h1(t-1)=h1_lds[cur]) --
            if (t >= 1) {
                const int s = l & 15;
                const float* hb = h1_lds[cur];
                float p = hb[s] * w2p0;
                p = fmaf(hb[s + 16], w2p1, p);
                p = fmaf(hb[s + 32], w2p2, p);
                p = fmaf(hb[s + 48], w2p3, p);
                p += __shfl_xor(p, 1);
                p += __shfl_xor(p, 2);
                p += __shfl_xor(p, 4);
                p += __shfl_xor(p, 8);
                zi_s = __shfl(p, s)      + b2v.x;
                zj_s = __shfl(p, s + 16) + b2v.y;
                zf_s = __shfl(p, s + 32) + b2v.z;
                zo_s = __shfl(p, s + 48) + b2v.w;
            }
        }
        __syncthreads();
        cur = nxt;
    }

    // ---- epilogue (wave 4): finish steps T-2 and T-1 ----
    if (w == 4) {
        {
            const float zi = zi_s + h2 * w2t.x;
            const float zj = zj_s + h2 * w2t.y;
            const float zf = zf_s + h2 * w2t.z;
            const float zo = zo_s + h2 * w2t.w;
            c2 = fast_sig(zf + 1.0f) * c2 + fast_sig(zi) * fast_tanh(zj);
            h2 = fast_sig(zo) * fast_tanh(c2);
            if (l == 0) outg[kT - 2] = h2;
        }
        {
            const int s = l & 15;
            const float* hb = h1_lds[cur];
            float p = hb[s] * w2p0;
            p = fmaf(hb[s + 16], w2p1, p);
            p = fmaf(hb[s + 32], w2p2, p);
            p = fmaf(hb[s + 48], w2p3, p);
            p += __shfl_xor(p, 1);
            p += __shfl_xor(p, 2);
            p += __shfl_xor(p, 4);
            p += __shfl_xor(p, 8);
            const float zi = __shfl(p, s)      + b2v.x + h2 * w2t.x;
            const float zj = __shfl(p, s + 16) + b2v.y + h2 * w2t.y;
            const float zf = __shfl(p, s + 32) + b2v.z + h2 * w2t.z;
            const float zo = __shfl(p, s + 48) + b2v.w + h2 * w2t.w;
            c2 = fast_sig(zf + 1.0f) * c2 + fast_sig(zi) * fast_tanh(zj);
            h2 = fast_sig(zo) * fast_tanh(c2);
            if (l == 0) outg[kT - 1] = h2;
        }
    }
}

extern "C" void kernel_launch(void* const* d_in, const int* in_sizes, int n_in,
                              void* d_out, int out_size, void* d_ws, size_t ws_size,
                              hipStream_t stream) {
    const float* x  = (const float*)d_in[0];
    const float* W1 = (const float*)d_in[1];
    const float* b1 = (const float*)d_in[2];
    const float* W2 = (const float*)d_in[3];
    const float* b2 = (const float*)d_in[4];
    float* out = (float*)d_out;
    lstm2_kernel<<<kB, 320, 0, stream>>>(x, W1, b1, W2, b2, out);
}